// Round 6
// baseline (680.807 us; speedup 1.0000x reference)
//
#include <hip/hip_runtime.h>
#include <hip/hip_bf16.h>
#include <math.h>

#define N_NODES 16384
#define N_EDGES 65536
#define N_GRAPH 128
#define TNF 32      // nodes per k_fused block
#define KC 4        // k-chunk size
#define NCH 16      // 64 / KC (chunk NCH = bias chunk, k=64 packed from b2)
#define CAP 160     // staged-edge capacity per 32-node tile (mean 128)
#define MREG 10     // register message slots per 16-lane group (CAP/16)
#define E4 (N_EDGES * 4)
#define LFRAG 278528   // per-layer packed fragment size in shorts: 68*2*4*64*8

typedef short s8v __attribute__((ext_vector_type(8)));
typedef float f4v __attribute__((ext_vector_type(4)));

// bf16 3-plane split: v = h + m + l + O(2^-24 v). bf16 shares fp32 exponent
// range -> no denormal hazards (fp16's failure mode in rounds 4/5).
__device__ __forceinline__ void splitw3(float v, unsigned short* h,
                                        unsigned short* m, unsigned short* l) {
    __hip_bfloat16 a = __float2bfloat16(v);
    float r1 = v - __bfloat162float(a);
    __hip_bfloat16 b = __float2bfloat16(r1);
    float r2 = r1 - __bfloat162float(b);
    __hip_bfloat16 c = __float2bfloat16(r2);
    *h = *reinterpret_cast<unsigned short*>(&a);
    *m = *reinterpret_cast<unsigned short*>(&b);
    *l = *reinterpret_cast<unsigned short*>(&c);
}

// ---------------------------------------------------------------- CSR build
__global__ __launch_bounds__(256) void k_hist(const int* __restrict__ esrc,
                                              const int* __restrict__ edst,
                                              int* __restrict__ deg,
                                              int* __restrict__ cntd) {
    int i = blockIdx.x * 256 + threadIdx.x;
    if (i < N_EDGES) {
        atomicAdd(&deg[esrc[i]], 1);
        atomicAdd(&cntd[edst[i]], 1);
    }
}

// dual scan: block 0: deg->soff/cursor ; block 1: cntd->doff/cursor2
__global__ __launch_bounds__(256) void k_scan2(const int* __restrict__ deg,
                                               const int* __restrict__ cntd,
                                               int* __restrict__ soff,
                                               int* __restrict__ doff,
                                               int* __restrict__ cur1,
                                               int* __restrict__ cur2) {
    const int* in = blockIdx.x ? cntd : deg;
    int* offs = blockIdx.x ? doff : soff;
    int* cur = blockIdx.x ? cur2 : cur1;
    __shared__ int part[256];
    int tid = threadIdx.x;
    int base = tid * 64;
    int s = 0;
    for (int i = 0; i < 64; ++i) s += in[base + i];
    part[tid] = s;
    __syncthreads();
    for (int d = 1; d < 256; d <<= 1) {
        int add = (tid >= d) ? part[tid - d] : 0;
        __syncthreads();
        part[tid] += add;
        __syncthreads();
    }
    int run = (tid == 0) ? 0 : part[tid - 1];
    for (int i = 0; i < 64; ++i) {
        offs[base + i] = run;
        cur[base + i] = run;
        run += in[base + i];
    }
    if (tid == 255) offs[N_NODES] = run;
}

__global__ __launch_bounds__(256) void k_fill_src(const int* __restrict__ esrc,
                                                  int* __restrict__ cursor,
                                                  int* __restrict__ ebs) {
    int i = blockIdx.x * 256 + threadIdx.x;
    if (i < N_EDGES) {
        int p = atomicAdd(&cursor[esrc[i]], 1);
        ebs[p] = i;
    }
}

// deterministic canonicalization: insertion-sort each segment ascending
__global__ __launch_bounds__(256) void k_sortseg(const int* __restrict__ offs,
                                                 int* __restrict__ arr) {
    int n = blockIdx.x * 256 + threadIdx.x;
    if (n >= N_NODES) return;
    int a = offs[n], b = offs[n + 1];
    for (int i = a + 1; i < b; ++i) {
        int v = arr[i], j = i - 1;
        while (j >= a && arr[j] > v) { arr[j + 1] = arr[j]; --j; }
        arr[j + 1] = v;
    }
}

// dst-CSR of (sorted) src-CSR positions
__global__ __launch_bounds__(256) void k_fill_dl(const int* __restrict__ ebs,
                                                 const int* __restrict__ edst,
                                                 int* __restrict__ cursor2,
                                                 int* __restrict__ dlist) {
    int pos = blockIdx.x * 256 + threadIdx.x;
    if (pos < N_EDGES) {
        int e = ebs[pos];
        int p2 = atomicAdd(&cursor2[edst[e]], 1);
        dlist[p2] = pos;
    }
}

// ---------------------------------------------------- w2 (+b2) fragment pack
// 68 "k" rows per layer: k<64 from w2, k==64 from b2, k>64 zeros.
// Fragment layout (shorts): l*LFRAG + ((k*2+s)*4+o16)*512 + lane*8 + j
//   element = row[(s*32 + (lane>>4)*8 + j)*64 + o16*16 + (lane&15)]
__global__ __launch_bounds__(256) void k_w2prep(const float* __restrict__ w2,
                                                const float* __restrict__ b2,
                                                unsigned short* __restrict__ w2fh,
                                                unsigned short* __restrict__ w2fm,
                                                unsigned short* __restrict__ w2fl) {
    __shared__ float sb[4096];
    int bid = blockIdx.x;
    int l = bid / 68, k = bid % 68;
    int tid = threadIdx.x;
    const float* src = nullptr;
    if (k < 64) src = w2 + (size_t)(l * 64 + k) * 4096;
    else if (k == 64) src = b2 + (size_t)l * 4096;
    if (src) {
        for (int i = 0; i < 4; ++i)
            *(f4v*)&sb[tid * 16 + i * 4] = *(const f4v*)(src + tid * 16 + i * 4);
    } else {
        for (int i = 0; i < 16; ++i) sb[tid * 16 + i] = 0.f;
    }
    __syncthreads();
    for (int slot = tid; slot < 512; slot += 256) {
        int s = slot >> 8;
        int rem = slot & 255;
        int o16 = rem >> 6;
        int lane = rem & 63;
        int frag = (k * 2 + s) * 4 + o16;
        unsigned short hv[8], mv[8], lv[8];
#pragma unroll
        for (int j = 0; j < 8; ++j) {
            float v = sb[(s * 32 + (lane >> 4) * 8 + j) * 64 + o16 * 16 + (lane & 15)];
            splitw3(v, &hv[j], &mv[j], &lv[j]);
        }
        size_t off = (size_t)l * LFRAG + frag * 512 + lane * 8;
#pragma unroll
        for (int j = 0; j < 8; ++j) {
            w2fh[off + j] = hv[j];
            w2fm[off + j] = mv[j];
            w2fl[off + j] = lv[j];
        }
    }
}

// ---------------------------------------------------------- lin0 row-GEMM
__global__ __launch_bounds__(256) void k_lin0(const float* __restrict__ xin,
                                              const float* __restrict__ w,
                                              const float* __restrict__ b,
                                              float* __restrict__ xout,
                                              unsigned short* __restrict__ xh,
                                              unsigned short* __restrict__ xm,
                                              unsigned short* __restrict__ xl) {
    __shared__ float As[64][64];
    __shared__ float Ws[64][64];
    __shared__ float bs[64];
    int tid = threadIdx.x;
    int n0 = blockIdx.x * 64;
    for (int i = tid; i < 1024; i += 256) {
        *(f4v*)&As[0][i * 4] = *(const f4v*)(xin + n0 * 64 + i * 4);
        *(f4v*)&Ws[0][i * 4] = *(const f4v*)(w + i * 4);
    }
    if (tid < 64) bs[tid] = b[tid];
    __syncthreads();
    int o = tid & 63, rr = tid >> 6;
    float acc[16];
#pragma unroll
    for (int i = 0; i < 16; ++i) acc[i] = bs[o];
    for (int d = 0; d < 64; ++d) {
        float wv = Ws[d][o];
#pragma unroll
        for (int i = 0; i < 16; ++i) acc[i] += As[rr * 16 + i][d] * wv;
    }
    for (int i = 0; i < 16; ++i) {
        int idx = (n0 + rr * 16 + i) * 64 + o;
        float v = fmaxf(acc[i], 0.f);
        xout[idx] = v;
        splitw3(v, &xh[idx], &xm[idx], &xl[idx]);
    }
}

// ------------------------- edge MLP, CSR-ordered chunk-major output
// h_s[c][pos][j] = relu(ea[ebs[pos]]@w1+b1)[c*4+j]
__global__ __launch_bounds__(256) void k_hgemm(const float* __restrict__ ea,
                                               const float* __restrict__ w1,
                                               const float* __restrict__ b1,
                                               const int* __restrict__ ebs,
                                               float* __restrict__ h_s) {
    __shared__ float w1s[1024];
    __shared__ float b1s[64];
    __shared__ int eids[64];
    __shared__ float eas[64][20];  // padded
    int tid = threadIdx.x;
    int pos0 = blockIdx.x * 64;
    *(f4v*)&w1s[tid * 4] = *(const f4v*)(w1 + tid * 4);
    if (tid < 64) {
        b1s[tid] = b1[tid];
        eids[tid] = ebs[pos0 + tid];
    }
    __syncthreads();
    {
        int e = tid >> 2, part = tid & 3;
        f4v v = *(const f4v*)(ea + (size_t)eids[e] * 16 + part * 4);
        *(f4v*)&eas[e][part * 4] = v;
    }
    __syncthreads();
    int edge = tid >> 2, o16 = tid & 3;
    float acc[16];
#pragma unroll
    for (int j = 0; j < 16; ++j) acc[j] = b1s[o16 * 16 + j];
    for (int k = 0; k < 16; ++k) {
        float a = eas[edge][k];
#pragma unroll
        for (int j = 0; j < 16; ++j) acc[j] += a * w1s[k * 64 + o16 * 16 + j];
    }
    int pos = pos0 + edge;
#pragma unroll
    for (int cc = 0; cc < 4; ++cc) {
        int c = o16 * 4 + cc;
        f4v v;
#pragma unroll
        for (int j = 0; j < 4; ++j) v[j] = fmaxf(acc[cc * 4 + j], 0.f);
        *(f4v*)(h_s + c * E4 + pos * 4) = v;
    }
}

// ------------------------------------------------------------ fused NNConv
// B fragments for one o16-half of one k-row: [plane][s][o_in_half]
__device__ __forceinline__ void loadBh(int k, int ho, int lane,
                                       const unsigned short* __restrict__ wh,
                                       const unsigned short* __restrict__ wm,
                                       const unsigned short* __restrict__ wl,
                                       s8v (&B)[3][2][2]) {
#pragma unroll
    for (int s = 0; s < 2; ++s)
#pragma unroll
        for (int oo = 0; oo < 2; ++oo) {
            int fo = ((k * 2 + s) * 4 + (ho * 2 + oo)) * 512 + lane * 8;
            B[0][s][oo] = *(const s8v*)(wh + fo);
            B[1][s][oo] = *(const s8v*)(wm + fo);
            B[2][s][oo] = *(const s8v*)(wl + fo);
        }
}

__global__ __launch_bounds__(256, 2) void k_fused(
    const unsigned short* __restrict__ xh, const unsigned short* __restrict__ xm,
    const unsigned short* __restrict__ xl,
    const unsigned short* __restrict__ w2fh, const unsigned short* __restrict__ w2fm,
    const unsigned short* __restrict__ w2fl,
    const float* __restrict__ h_s, const int* __restrict__ soff,
    const int* __restrict__ ebs, const int* __restrict__ esrc,
    float* __restrict__ msg) {
    __shared__ __align__(16) float P[2][KC][TNF][68];  // 69.6 KB
    __shared__ __align__(16) float hC[2][CAP][4];      // 5 KB
    __shared__ short elt[CAP];

    const int tid = threadIdx.x;
    const int n0 = blockIdx.x * TNF;
    const int w = tid >> 6;
    const int lane = tid & 63;
    const int l15 = tid & 15;
    const int q = lane >> 4;
    const int grp = tid >> 4;

    const int e0 = soff[n0];
    const int cnt_full = soff[n0 + TNF] - e0;
    const int cnt = min(cnt_full, CAP);

    for (int i = tid; i < cnt; i += 256) elt[i] = (short)(esrc[ebs[e0 + i]] - n0);
    if (tid < cnt)
        *(f4v*)&hC[0][tid][0] = *(const f4v*)(h_s + (e0 + tid) * 4);

    // A fragments: 3 bf16 planes, whole-kernel lifetime
    s8v A[3][2][2];  // [plane][rt][s]
#pragma unroll
    for (int rt = 0; rt < 2; ++rt)
#pragma unroll
        for (int s = 0; s < 2; ++s) {
            int n = n0 + rt * 16 + l15;
            int d0 = s * 32 + q * 8;
            A[0][rt][s] = *(const s8v*)(xh + n * 64 + d0);
            A[1][rt][s] = *(const s8v*)(xm + n * 64 + d0);
            A[2][rt][s] = *(const s8v*)(xl + n * 64 + d0);
        }

    s8v B0[3][2][2], B1[3][2][2];
    loadBh(w, 0, lane, w2fh, w2fm, w2fl, B0);  // chunk 0, half 0

    const int cpg = (cnt + 15) >> 4;
    const int ib = grp * cpg;
    const int ie = min(ib + cpg, cnt);
    f4v m[MREG];
#pragma unroll
    for (int il = 0; il < MREG; ++il) m[il] = (f4v)0.f;

    __syncthreads();

    // 6-term 3-plane MFMA for one o16-half: P += (h+m+l)x * (h+m+l)w, drop m*l,l*m,l*l
    auto mfma_half = [&](s8v(&B)[3][2][2], int buf, int ho) {
#pragma unroll
        for (int rt = 0; rt < 2; ++rt) {
            f4v acc[2];
            acc[0] = (f4v)0.f;
            acc[1] = (f4v)0.f;
#pragma unroll
            for (int s = 0; s < 2; ++s)
#pragma unroll
                for (int oo = 0; oo < 2; ++oo) {
                    acc[oo] = __builtin_amdgcn_mfma_f32_16x16x32_bf16(A[0][rt][s], B[0][s][oo], acc[oo], 0, 0, 0);
                    acc[oo] = __builtin_amdgcn_mfma_f32_16x16x32_bf16(A[0][rt][s], B[1][s][oo], acc[oo], 0, 0, 0);
                    acc[oo] = __builtin_amdgcn_mfma_f32_16x16x32_bf16(A[1][rt][s], B[0][s][oo], acc[oo], 0, 0, 0);
                    acc[oo] = __builtin_amdgcn_mfma_f32_16x16x32_bf16(A[1][rt][s], B[1][s][oo], acc[oo], 0, 0, 0);
                    acc[oo] = __builtin_amdgcn_mfma_f32_16x16x32_bf16(A[0][rt][s], B[2][s][oo], acc[oo], 0, 0, 0);
                    acc[oo] = __builtin_amdgcn_mfma_f32_16x16x32_bf16(A[2][rt][s], B[0][s][oo], acc[oo], 0, 0, 0);
                }
#pragma unroll
            for (int oo = 0; oo < 2; ++oo)
#pragma unroll
                for (int r = 0; r < 4; ++r)
                    P[buf][w][rt * 16 + q * 4 + r][(ho * 2 + oo) * 16 + l15] = acc[oo][r];
        }
    };

    for (int c = 0; c <= NCH; ++c) {
        const int buf = c & 1;
        const int k = c * KC + w;
        // ---- phase 1 with half-granularity B prefetch
        loadBh(k, 1, lane, w2fh, w2fm, w2fl, B1);        // this chunk, half 1
        mfma_half(B0, buf, 0);
        if (c < NCH) loadBh((c + 1) * KC + w, 0, lane, w2fh, w2fm, w2fl, B0);  // next chunk, half 0
        f4v hn = (f4v)0.f;
        const bool hok = (c + 1 < NCH) && (tid < cnt);
        if (hok) hn = *(const f4v*)(h_s + (c + 1) * E4 + (e0 + tid) * 4);
        mfma_half(B1, buf, 1);
        __syncthreads();
        // ---- phase 2
        if (c < NCH) {
            int tp = -1;
            f4v p0 = (f4v)0.f, p1 = (f4v)0.f, p2 = (f4v)0.f, p3 = (f4v)0.f;
#pragma unroll
            for (int il = 0; il < MREG; ++il) {
                int i = ib + il;
                if (i < ie) {
                    int t = elt[i];
                    if (t != tp) {
                        p0 = *(const f4v*)&P[buf][0][t][l15 * 4];
                        p1 = *(const f4v*)&P[buf][1][t][l15 * 4];
                        p2 = *(const f4v*)&P[buf][2][t][l15 * 4];
                        p3 = *(const f4v*)&P[buf][3][t][l15 * 4];
                        tp = t;
                    }
                    f4v hv = *(const f4v*)&hC[buf][i][0];
                    m[il] += p0 * hv[0] + p1 * hv[1] + p2 * hv[2] + p3 * hv[3];
                }
            }
            for (int i = CAP + grp; i < cnt_full; i += 16) {  // rare overflow
                int pos = e0 + i;
                int t = esrc[ebs[pos]] - n0;
                f4v hv = *(const f4v*)(h_s + c * E4 + pos * 4);
                f4v part = *(const f4v*)&P[buf][0][t][l15 * 4] * hv[0] +
                           *(const f4v*)&P[buf][1][t][l15 * 4] * hv[1] +
                           *(const f4v*)&P[buf][2][t][l15 * 4] * hv[2] +
                           *(const f4v*)&P[buf][3][t][l15 * 4] * hv[3];
                float* mp = msg + pos * 64 + l15 * 4;
                if (c == 0) *(f4v*)mp = part;
                else *(f4v*)mp = *(const f4v*)mp + part;
            }
        } else {  // bias chunk: hv == (1,0,0,0)
#pragma unroll
            for (int il = 0; il < MREG; ++il) {
                int i = ib + il;
                if (i < ie) m[il] += *(const f4v*)&P[buf][0][elt[i]][l15 * 4];
            }
            for (int i = CAP + grp; i < cnt_full; i += 16) {
                int pos = e0 + i;
                int t = esrc[ebs[pos]] - n0;
                float* mp = msg + pos * 64 + l15 * 4;
                *(f4v*)mp = *(const f4v*)mp + *(const f4v*)&P[buf][0][t][l15 * 4];
            }
        }
        // stage next h slab (post-barrier, opposite parity vs readers)
        if (hok) *(f4v*)&hC[(c + 1) & 1][tid][0] = hn;
    }

    // flush register messages, coalesced
#pragma unroll
    for (int il = 0; il < MREG; ++il) {
        int i = ib + il;
        if (i < ie) *(f4v*)(msg + (e0 + i) * 64 + l15 * 4) = m[il];
    }
}

// -------- NNConv root GEMM + dst-gather mean + GraphNorm + residual + split
__global__ __launch_bounds__(256) void k_conv_gn(
    const float* __restrict__ msg, const int* __restrict__ dlist,
    const int* __restrict__ doff, const float* __restrict__ rootw,
    const float* __restrict__ convb, const float* __restrict__ gnsc,
    const float* __restrict__ gnw, const float* __restrict__ gnb,
    float* __restrict__ xb, unsigned short* __restrict__ xh,
    unsigned short* __restrict__ xm, unsigned short* __restrict__ xl) {
    __shared__ float xs[128][64];
    __shared__ float Ws[64][64];
    __shared__ float xcs[128][64];
    __shared__ float r1[4][64], r2[4][64], mv[64], rs[64];
    int g = blockIdx.x, tid = threadIdx.x;
    int o = tid & 63, rr = tid >> 6;
    int base = g * 128 * 64;
    for (int i = tid; i < 2048; i += 256) {
        *(f4v*)&xs[0][i * 4] = *(const f4v*)(xb + base + i * 4);
        if (i < 1024) *(f4v*)&Ws[0][i * 4] = *(const f4v*)(rootw + i * 4);
    }
    __syncthreads();
    float cb = convb[o];
    float ls = 0.f, ls2 = 0.f;
    for (int r = rr; r < 128; r += 4) {
        float acc = cb;
        for (int d = 0; d < 64; ++d) acc += xs[r][d] * Ws[d][o];
        int n = g * 128 + r;
        int pa = doff[n], pb = doff[n + 1];
        float s = 0.f;
        for (int p = pa; p < pb; ++p) s += msg[(size_t)dlist[p] * 64 + o];
        acc += s / fmaxf((float)(pb - pa), 1.f);
        acc = fmaxf(acc, 0.f);
        xcs[r][o] = acc;
        ls += acc;
        ls2 += acc * acc;
    }
    r1[rr][o] = ls;
    r2[rr][o] = ls2;
    __syncthreads();
    if (tid < 64) {
        float sum = r1[0][tid] + r1[1][tid] + r1[2][tid] + r1[3][tid];
        float sum2 = r2[0][tid] + r2[1][tid] + r2[2][tid] + r2[3][tid];
        float m = sum * (1.f / 128.f);
        float ex2 = sum2 * (1.f / 128.f);
        float sc = gnsc[tid];
        float var = ex2 - (2.f * sc - sc * sc) * m * m;
        mv[tid] = m;
        rs[tid] = rsqrtf(var + 1e-5f);
    }
    __syncthreads();
    float sc = gnsc[o], wv = gnw[o], bv = gnb[o], mo = mv[o], rv = rs[o];
    for (int r = rr; r < 128; r += 4) {
        int idx = base + r * 64 + o;
        float xn = wv * (xcs[r][o] - sc * mo) * rv + bv + xs[r][o];
        xb[idx] = xn;
        splitw3(xn, &xh[idx], &xm[idx], &xl[idx]);
    }
}

// ------------------------------------- Set2Set (3 steps) + head, one kernel
__global__ __launch_bounds__(256) void k_s2s(const float* __restrict__ x,
                                             const float* __restrict__ wih,
                                             const float* __restrict__ whh,
                                             const float* __restrict__ bih,
                                             const float* __restrict__ bhh,
                                             const float* __restrict__ hw1,
                                             const float* __restrict__ hb1,
                                             const float* __restrict__ hw2,
                                             const float* __restrict__ hb2,
                                             float* __restrict__ out) {
    int g = blockIdx.x, tid = threadIdx.x;
    __shared__ float xg[128][64];
    __shared__ float qs[128];
    __shared__ float hhS[64], ccS[64];
    __shared__ float gl[256];
    __shared__ float ev[128];
    __shared__ float S[4][64];
    __shared__ float red[2];
    for (int i = tid; i < 8192; i += 256)
        xg[i >> 6][i & 63] = x[(g * 128 + (i >> 6)) * 64 + (i & 63)];
    if (tid < 128) qs[tid] = 0.f;
    if (tid < 64) { hhS[tid] = 0.f; ccS[tid] = 0.f; }
    __syncthreads();

    for (int step = 0; step < 3; ++step) {
        float acc = bih[tid] + bhh[tid];
        const float* wr = wih + tid * 128;
        for (int i = 0; i < 128; ++i) acc += qs[i] * wr[i];
        const float* w2r = whh + tid * 64;
        for (int i = 0; i < 64; ++i) acc += hhS[i] * w2r[i];
        gl[tid] = acc;
        __syncthreads();
        if (tid < 64) {
            float ig = 1.f / (1.f + expf(-gl[tid]));
            float fg = 1.f / (1.f + expf(-gl[64 + tid]));
            float gg = tanhf(gl[128 + tid]);
            float og = 1.f / (1.f + expf(-gl[192 + tid]));
            float cnew = fg * ccS[tid] + ig * gg;
            ccS[tid] = cnew;
            hhS[tid] = og * tanhf(cnew);
        }
        __syncthreads();
        if (tid < 128) {
            float s = 0.f;
            for (int c = 0; c < 64; ++c) s += xg[tid][c] * hhS[c];
            ev[tid] = s;
        }
        __syncthreads();
        if (tid < 64) {
            float mx = fmaxf(ev[tid], ev[tid + 64]);
            for (int off = 32; off > 0; off >>= 1) mx = fmaxf(mx, __shfl_down(mx, off));
            if (tid == 0) red[0] = mx;
        }
        __syncthreads();
        float emax = red[0];
        if (tid < 128) ev[tid] = expf(ev[tid] - emax);
        __syncthreads();
        if (tid < 64) {
            float sm = ev[tid] + ev[tid + 64];
            for (int off = 32; off > 0; off >>= 1) sm += __shfl_down(sm, off);
            if (tid == 0) red[1] = sm;
        }
        __syncthreads();
        float denom = red[1];
        int c = tid & 63, rr = tid >> 6;
        float p = 0.f;
        for (int n = rr; n < 128; n += 4) p += ev[n] * xg[n][c];
        S[rr][c] = p;
        __syncthreads();
        if (tid < 64) {
            float r = (S[0][tid] + S[1][tid] + S[2][tid] + S[3][tid]) / denom;
            qs[tid] = hhS[tid];
            qs[64 + tid] = r;
        }
        __syncthreads();
    }

    if (tid < 64) {
        float acc = hb1[tid];
        for (int i = 0; i < 128; ++i) acc += qs[i] * hw1[i * 64 + tid];
        acc = fmaxf(acc, 0.f);
        float v = acc * hw2[tid];
        for (int off = 32; off > 0; off >>= 1) v += __shfl_down(v, off);
        if (tid == 0) out[g] = v + hb2[0];
    }
}

// -------------------------------------------------------------------- launch
extern "C" void kernel_launch(void* const* d_in, const int* in_sizes, int n_in,
                              void* d_out, int out_size, void* d_ws, size_t ws_size,
                              hipStream_t stream) {
    (void)in_sizes; (void)n_in; (void)out_size; (void)ws_size;
    const float* x_in  = (const float*)d_in[0];
    const int*   eidx  = (const int*)d_in[1];
    const float* eattr = (const float*)d_in[2];
    const float* lin0w = (const float*)d_in[4];
    const float* lin0b = (const float*)d_in[5];
    const float* mw1   = (const float*)d_in[6];
    const float* mb1   = (const float*)d_in[7];
    const float* mw2   = (const float*)d_in[8];
    const float* mb2   = (const float*)d_in[9];
    const float* rootw = (const float*)d_in[10];
    const float* convb = (const float*)d_in[11];
    const float* gnw   = (const float*)d_in[12];
    const float* gnb   = (const float*)d_in[13];
    const float* gnsc  = (const float*)d_in[14];
    const float* wih   = (const float*)d_in[15];
    const float* whh   = (const float*)d_in[16];
    const float* bih   = (const float*)d_in[17];
    const float* bhh   = (const float*)d_in[18];
    const float* hw1   = (const float*)d_in[19];
    const float* hb1   = (const float*)d_in[20];
    const float* hw2   = (const float*)d_in[21];
    const float* hb2   = (const float*)d_in[22];
    float* out = (float*)d_out;

    const int* esrc = eidx;
    const int* edst = eidx + N_EDGES;

    float* xb  = (float*)d_ws;                 // 1,048,576 f
    float* h_s = xb + 1048576;                 // 4,194,304 f
    float* msg = h_s + 4194304;                // 4,194,304 f
    unsigned short* xh   = (unsigned short*)(msg + 4194304);  // 1,048,576 us each
    unsigned short* xm   = xh + 1048576;
    unsigned short* xl   = xm + 1048576;
    unsigned short* w2fh = xl + 1048576;       // 3*LFRAG us each
    unsigned short* w2fm = w2fh + 3 * LFRAG;
    unsigned short* w2fl = w2fm + 3 * LFRAG;
    int* deg     = (int*)(w2fl + 3 * LFRAG);
    int* cntd    = deg + N_NODES;
    int* soff    = cntd + N_NODES;
    int* doff    = soff + (N_NODES + 1);
    int* cursor  = doff + (N_NODES + 1);
    int* cursor2 = cursor + N_NODES;
    int* ebs     = cursor2 + N_NODES;
    int* dlist   = ebs + N_EDGES;

    hipMemsetAsync(deg, 0, sizeof(int) * 2 * N_NODES, stream);

    k_w2prep<<<3 * 68, 256, 0, stream>>>(mw2, mb2, w2fh, w2fm, w2fl);
    k_hist<<<N_EDGES / 256, 256, 0, stream>>>(esrc, edst, deg, cntd);
    k_scan2<<<2, 256, 0, stream>>>(deg, cntd, soff, doff, cursor, cursor2);
    k_fill_src<<<N_EDGES / 256, 256, 0, stream>>>(esrc, cursor, ebs);
    k_sortseg<<<N_NODES / 256, 256, 0, stream>>>(soff, ebs);
    k_fill_dl<<<N_EDGES / 256, 256, 0, stream>>>(ebs, edst, cursor2, dlist);
    k_sortseg<<<N_NODES / 256, 256, 0, stream>>>(doff, dlist);

    k_lin0<<<N_NODES / 64, 256, 0, stream>>>(x_in, lin0w, lin0b, xb, xh, xm, xl);

    for (int l = 0; l < 3; ++l) {
        k_hgemm<<<N_EDGES / 64, 256, 0, stream>>>(eattr, mw1 + l * 1024, mb1 + l * 64,
                                                  ebs, h_s);
        k_fused<<<N_NODES / TNF, 256, 0, stream>>>(
            xh, xm, xl,
            w2fh + (size_t)l * LFRAG, w2fm + (size_t)l * LFRAG, w2fl + (size_t)l * LFRAG,
            h_s, soff, ebs, esrc, msg);
        k_conv_gn<<<N_GRAPH, 256, 0, stream>>>(msg, dlist, doff, rootw + l * 4096,
                                               convb + l * 64, gnsc + l * 64,
                                               gnw + l * 64, gnb + l * 64, xb,
                                               xh, xm, xl);
    }

    k_s2s<<<N_GRAPH, 256, 0, stream>>>(xb, wih, whh, bih, bhh,
                                       hw1, hb1, hw2, hb2, out);
}

// Round 7
// 520.112 us; speedup vs baseline: 1.3090x; 1.3090x over previous
//
#include <hip/hip_runtime.h>
#include <hip/hip_bf16.h>
#include <math.h>

#define N_NODES 16384
#define N_EDGES 65536
#define N_GRAPH 128
#define TNF 32      // nodes per k_fused block
#define KC 4        // k-chunk size
#define NCH 16      // 64 / KC (chunk NCH = bias chunk, k=64 packed from b2)
#define CAP 160     // staged-edge capacity per 32-node tile (mean 128)
#define MREG 10     // register message slots per 16-lane group (CAP/16)
#define E4 (N_EDGES * 4)
#define LFRAG 278528   // per-layer packed fragment size in shorts: 68*2*4*64*8

typedef short s8v __attribute__((ext_vector_type(8)));
typedef float f4v __attribute__((ext_vector_type(4)));

// bf16 3-plane split: v = h + m + l + O(2^-24 v). bf16 shares fp32 exponent
// range -> no denormal hazards (fp16's failure mode in rounds 4/5).
__device__ __forceinline__ void splitw3(float v, unsigned short* h,
                                        unsigned short* m, unsigned short* l) {
    __hip_bfloat16 a = __float2bfloat16(v);
    float r1 = v - __bfloat162float(a);
    __hip_bfloat16 b = __float2bfloat16(r1);
    float r2 = r1 - __bfloat162float(b);
    __hip_bfloat16 c = __float2bfloat16(r2);
    *h = *reinterpret_cast<unsigned short*>(&a);
    *m = *reinterpret_cast<unsigned short*>(&b);
    *l = *reinterpret_cast<unsigned short*>(&c);
}

// ---------------------------------------------------------------- CSR build
__global__ __launch_bounds__(256) void k_hist(const int* __restrict__ esrc,
                                              const int* __restrict__ edst,
                                              int* __restrict__ deg,
                                              int* __restrict__ cntd) {
    int i = blockIdx.x * 256 + threadIdx.x;
    if (i < N_EDGES) {
        atomicAdd(&deg[esrc[i]], 1);
        atomicAdd(&cntd[edst[i]], 1);
    }
}

// dual scan: block 0: deg->soff/cursor ; block 1: cntd->doff/cursor2
__global__ __launch_bounds__(256) void k_scan2(const int* __restrict__ deg,
                                               const int* __restrict__ cntd,
                                               int* __restrict__ soff,
                                               int* __restrict__ doff,
                                               int* __restrict__ cur1,
                                               int* __restrict__ cur2) {
    const int* in = blockIdx.x ? cntd : deg;
    int* offs = blockIdx.x ? doff : soff;
    int* cur = blockIdx.x ? cur2 : cur1;
    __shared__ int part[256];
    int tid = threadIdx.x;
    int base = tid * 64;
    int s = 0;
    for (int i = 0; i < 64; ++i) s += in[base + i];
    part[tid] = s;
    __syncthreads();
    for (int d = 1; d < 256; d <<= 1) {
        int add = (tid >= d) ? part[tid - d] : 0;
        __syncthreads();
        part[tid] += add;
        __syncthreads();
    }
    int run = (tid == 0) ? 0 : part[tid - 1];
    for (int i = 0; i < 64; ++i) {
        offs[base + i] = run;
        cur[base + i] = run;
        run += in[base + i];
    }
    if (tid == 255) offs[N_NODES] = run;
}

__global__ __launch_bounds__(256) void k_fill_src(const int* __restrict__ esrc,
                                                  int* __restrict__ cursor,
                                                  int* __restrict__ ebs) {
    int i = blockIdx.x * 256 + threadIdx.x;
    if (i < N_EDGES) {
        int p = atomicAdd(&cursor[esrc[i]], 1);
        ebs[p] = i;
    }
}

// deterministic canonicalization: insertion-sort each segment ascending
__global__ __launch_bounds__(256) void k_sortseg(const int* __restrict__ offs,
                                                 int* __restrict__ arr) {
    int n = blockIdx.x * 256 + threadIdx.x;
    if (n >= N_NODES) return;
    int a = offs[n], b = offs[n + 1];
    for (int i = a + 1; i < b; ++i) {
        int v = arr[i], j = i - 1;
        while (j >= a && arr[j] > v) { arr[j + 1] = arr[j]; --j; }
        arr[j + 1] = v;
    }
}

// dst-CSR of (sorted) src-CSR positions
__global__ __launch_bounds__(256) void k_fill_dl(const int* __restrict__ ebs,
                                                 const int* __restrict__ edst,
                                                 int* __restrict__ cursor2,
                                                 int* __restrict__ dlist) {
    int pos = blockIdx.x * 256 + threadIdx.x;
    if (pos < N_EDGES) {
        int e = ebs[pos];
        int p2 = atomicAdd(&cursor2[edst[e]], 1);
        dlist[p2] = pos;
    }
}

// ---------------------------------------------------- w2 (+b2) fragment pack
// 68 "k" rows per layer: k<64 from w2, k==64 from b2, k>64 zeros.
// Fragment layout (shorts): l*LFRAG + ((k*2+s)*4+o16)*512 + lane*8 + j
//   element = row[(s*32 + (lane>>4)*8 + j)*64 + o16*16 + (lane&15)]
__global__ __launch_bounds__(256) void k_w2prep(const float* __restrict__ w2,
                                                const float* __restrict__ b2,
                                                unsigned short* __restrict__ w2fh,
                                                unsigned short* __restrict__ w2fm,
                                                unsigned short* __restrict__ w2fl) {
    __shared__ float sb[4096];
    int bid = blockIdx.x;
    int l = bid / 68, k = bid % 68;
    int tid = threadIdx.x;
    const float* src = nullptr;
    if (k < 64) src = w2 + (size_t)(l * 64 + k) * 4096;
    else if (k == 64) src = b2 + (size_t)l * 4096;
    if (src) {
        for (int i = 0; i < 4; ++i)
            *(f4v*)&sb[tid * 16 + i * 4] = *(const f4v*)(src + tid * 16 + i * 4);
    } else {
        for (int i = 0; i < 16; ++i) sb[tid * 16 + i] = 0.f;
    }
    __syncthreads();
    for (int slot = tid; slot < 512; slot += 256) {
        int s = slot >> 8;
        int rem = slot & 255;
        int o16 = rem >> 6;
        int lane = rem & 63;
        int frag = (k * 2 + s) * 4 + o16;
        unsigned short hv[8], mv[8], lv[8];
#pragma unroll
        for (int j = 0; j < 8; ++j) {
            float v = sb[(s * 32 + (lane >> 4) * 8 + j) * 64 + o16 * 16 + (lane & 15)];
            splitw3(v, &hv[j], &mv[j], &lv[j]);
        }
        size_t off = (size_t)l * LFRAG + frag * 512 + lane * 8;
#pragma unroll
        for (int j = 0; j < 8; ++j) {
            w2fh[off + j] = hv[j];
            w2fm[off + j] = mv[j];
            w2fl[off + j] = lv[j];
        }
    }
}

// ---------------------------------------------------------- lin0 row-GEMM
__global__ __launch_bounds__(256) void k_lin0(const float* __restrict__ xin,
                                              const float* __restrict__ w,
                                              const float* __restrict__ b,
                                              float* __restrict__ xout,
                                              unsigned short* __restrict__ xh,
                                              unsigned short* __restrict__ xm,
                                              unsigned short* __restrict__ xl) {
    __shared__ float As[64][64];
    __shared__ float Ws[64][64];
    __shared__ float bs[64];
    int tid = threadIdx.x;
    int n0 = blockIdx.x * 64;
    for (int i = tid; i < 1024; i += 256) {
        *(f4v*)&As[0][i * 4] = *(const f4v*)(xin + n0 * 64 + i * 4);
        *(f4v*)&Ws[0][i * 4] = *(const f4v*)(w + i * 4);
    }
    if (tid < 64) bs[tid] = b[tid];
    __syncthreads();
    int o = tid & 63, rr = tid >> 6;
    float acc[16];
#pragma unroll
    for (int i = 0; i < 16; ++i) acc[i] = bs[o];
    for (int d = 0; d < 64; ++d) {
        float wv = Ws[d][o];
#pragma unroll
        for (int i = 0; i < 16; ++i) acc[i] += As[rr * 16 + i][d] * wv;
    }
    for (int i = 0; i < 16; ++i) {
        int idx = (n0 + rr * 16 + i) * 64 + o;
        float v = fmaxf(acc[i], 0.f);
        xout[idx] = v;
        splitw3(v, &xh[idx], &xm[idx], &xl[idx]);
    }
}

// ------------------------- edge MLP, CSR-ordered chunk-major output
// h_s[c][pos][j] = relu(ea[ebs[pos]]@w1+b1)[c*4+j]
__global__ __launch_bounds__(256) void k_hgemm(const float* __restrict__ ea,
                                               const float* __restrict__ w1,
                                               const float* __restrict__ b1,
                                               const int* __restrict__ ebs,
                                               float* __restrict__ h_s) {
    __shared__ float w1s[1024];
    __shared__ float b1s[64];
    __shared__ int eids[64];
    __shared__ float eas[64][20];  // padded
    int tid = threadIdx.x;
    int pos0 = blockIdx.x * 64;
    *(f4v*)&w1s[tid * 4] = *(const f4v*)(w1 + tid * 4);
    if (tid < 64) {
        b1s[tid] = b1[tid];
        eids[tid] = ebs[pos0 + tid];
    }
    __syncthreads();
    {
        int e = tid >> 2, part = tid & 3;
        f4v v = *(const f4v*)(ea + (size_t)eids[e] * 16 + part * 4);
        *(f4v*)&eas[e][part * 4] = v;
    }
    __syncthreads();
    int edge = tid >> 2, o16 = tid & 3;
    float acc[16];
#pragma unroll
    for (int j = 0; j < 16; ++j) acc[j] = b1s[o16 * 16 + j];
    for (int k = 0; k < 16; ++k) {
        float a = eas[edge][k];
#pragma unroll
        for (int j = 0; j < 16; ++j) acc[j] += a * w1s[k * 64 + o16 * 16 + j];
    }
    int pos = pos0 + edge;
#pragma unroll
    for (int cc = 0; cc < 4; ++cc) {
        int c = o16 * 4 + cc;
        f4v v;
#pragma unroll
        for (int j = 0; j < 4; ++j) v[j] = fmaxf(acc[cc * 4 + j], 0.f);
        *(f4v*)(h_s + c * E4 + pos * 4) = v;
    }
}

// ------------------------------------------------------------ fused NNConv
// B fragments for one o16-half of one k-row: [plane][s][o_in_half]
__device__ __forceinline__ void loadBh(int k, int ho, int lane,
                                       const unsigned short* __restrict__ wh,
                                       const unsigned short* __restrict__ wm,
                                       const unsigned short* __restrict__ wl,
                                       s8v (&B)[3][2][2]) {
#pragma unroll
    for (int s = 0; s < 2; ++s)
#pragma unroll
        for (int oo = 0; oo < 2; ++oo) {
            int fo = ((k * 2 + s) * 4 + (ho * 2 + oo)) * 512 + lane * 8;
            B[0][s][oo] = *(const s8v*)(wh + fo);
            B[1][s][oo] = *(const s8v*)(wm + fo);
            B[2][s][oo] = *(const s8v*)(wl + fo);
        }
}

__global__ __launch_bounds__(256, 2) void k_fused(
    const unsigned short* __restrict__ xh, const unsigned short* __restrict__ xm,
    const unsigned short* __restrict__ xl,
    const unsigned short* __restrict__ w2fh, const unsigned short* __restrict__ w2fm,
    const unsigned short* __restrict__ w2fl,
    const float* __restrict__ h_s, const int* __restrict__ soff,
    const int* __restrict__ ebs, const int* __restrict__ esrc,
    float* __restrict__ msg) {
    __shared__ __align__(16) float P[2][KC][TNF][68];  // 69.6 KB
    __shared__ __align__(16) float hC[2][CAP][4];      // 5 KB
    __shared__ short elt[CAP];

    const int tid = threadIdx.x;
    const int n0 = blockIdx.x * TNF;
    const int w = tid >> 6;
    const int lane = tid & 63;
    const int l15 = tid & 15;
    const int q = lane >> 4;
    const int grp = tid >> 4;

    const int e0 = soff[n0];
    const int cnt_full = soff[n0 + TNF] - e0;
    const int cnt = min(cnt_full, CAP);

    for (int i = tid; i < cnt; i += 256) elt[i] = (short)(esrc[ebs[e0 + i]] - n0);
    if (tid < cnt)
        *(f4v*)&hC[0][tid][0] = *(const f4v*)(h_s + (e0 + tid) * 4);

    // A fragments: 3 bf16 planes, whole-kernel lifetime
    s8v A[3][2][2];  // [plane][rt][s]
#pragma unroll
    for (int rt = 0; rt < 2; ++rt)
#pragma unroll
        for (int s = 0; s < 2; ++s) {
            int n = n0 + rt * 16 + l15;
            int d0 = s * 32 + q * 8;
            A[0][rt][s] = *(const s8v*)(xh + n * 64 + d0);
            A[1][rt][s] = *(const s8v*)(xm + n * 64 + d0);
            A[2][rt][s] = *(const s8v*)(xl + n * 64 + d0);
        }

    s8v B0[3][2][2], B1[3][2][2];
    loadBh(w, 0, lane, w2fh, w2fm, w2fl, B0);  // chunk 0, half 0

    const int cpg = (cnt + 15) >> 4;
    const int ib = grp * cpg;
    const int ie = min(ib + cpg, cnt);
    f4v m[MREG];
#pragma unroll
    for (int il = 0; il < MREG; ++il) m[il] = (f4v)0.f;

    __syncthreads();

    // 6-term 3-plane MFMA for one o16-half: P += (h+m+l)x * (h+m+l)w, drop m*l,l*m,l*l
    auto mfma_half = [&](s8v(&B)[3][2][2], int buf, int ho) {
#pragma unroll
        for (int rt = 0; rt < 2; ++rt) {
            f4v acc[2];
            acc[0] = (f4v)0.f;
            acc[1] = (f4v)0.f;
#pragma unroll
            for (int s = 0; s < 2; ++s)
#pragma unroll
                for (int oo = 0; oo < 2; ++oo) {
                    acc[oo] = __builtin_amdgcn_mfma_f32_16x16x32_bf16(A[0][rt][s], B[0][s][oo], acc[oo], 0, 0, 0);
                    acc[oo] = __builtin_amdgcn_mfma_f32_16x16x32_bf16(A[0][rt][s], B[1][s][oo], acc[oo], 0, 0, 0);
                    acc[oo] = __builtin_amdgcn_mfma_f32_16x16x32_bf16(A[1][rt][s], B[0][s][oo], acc[oo], 0, 0, 0);
                    acc[oo] = __builtin_amdgcn_mfma_f32_16x16x32_bf16(A[1][rt][s], B[1][s][oo], acc[oo], 0, 0, 0);
                    acc[oo] = __builtin_amdgcn_mfma_f32_16x16x32_bf16(A[0][rt][s], B[2][s][oo], acc[oo], 0, 0, 0);
                    acc[oo] = __builtin_amdgcn_mfma_f32_16x16x32_bf16(A[2][rt][s], B[0][s][oo], acc[oo], 0, 0, 0);
                }
#pragma unroll
            for (int oo = 0; oo < 2; ++oo)
#pragma unroll
                for (int r = 0; r < 4; ++r)
                    P[buf][w][rt * 16 + q * 4 + r][(ho * 2 + oo) * 16 + l15] = acc[oo][r];
        }
    };

    for (int c = 0; c <= NCH; ++c) {
        const int buf = c & 1;
        const int k = c * KC + w;
        // ---- phase 1 with half-granularity B prefetch
        loadBh(k, 1, lane, w2fh, w2fm, w2fl, B1);        // this chunk, half 1
        mfma_half(B0, buf, 0);
        if (c < NCH) loadBh((c + 1) * KC + w, 0, lane, w2fh, w2fm, w2fl, B0);  // next chunk, half 0
        f4v hn = (f4v)0.f;
        const bool hok = (c + 1 < NCH) && (tid < cnt);
        if (hok) hn = *(const f4v*)(h_s + (c + 1) * E4 + (e0 + tid) * 4);
        mfma_half(B1, buf, 1);
        __syncthreads();
        // ---- phase 2
        if (c < NCH) {
            int tp = -1;
            f4v p0 = (f4v)0.f, p1 = (f4v)0.f, p2 = (f4v)0.f, p3 = (f4v)0.f;
#pragma unroll
            for (int il = 0; il < MREG; ++il) {
                int i = ib + il;
                if (i < ie) {
                    int t = elt[i];
                    if (t != tp) {
                        p0 = *(const f4v*)&P[buf][0][t][l15 * 4];
                        p1 = *(const f4v*)&P[buf][1][t][l15 * 4];
                        p2 = *(const f4v*)&P[buf][2][t][l15 * 4];
                        p3 = *(const f4v*)&P[buf][3][t][l15 * 4];
                        tp = t;
                    }
                    f4v hv = *(const f4v*)&hC[buf][i][0];
                    m[il] += p0 * hv[0] + p1 * hv[1] + p2 * hv[2] + p3 * hv[3];
                }
            }
            for (int i = CAP + grp; i < cnt_full; i += 16) {  // rare overflow
                int pos = e0 + i;
                int t = esrc[ebs[pos]] - n0;
                f4v hv = *(const f4v*)(h_s + c * E4 + pos * 4);
                f4v part = *(const f4v*)&P[buf][0][t][l15 * 4] * hv[0] +
                           *(const f4v*)&P[buf][1][t][l15 * 4] * hv[1] +
                           *(const f4v*)&P[buf][2][t][l15 * 4] * hv[2] +
                           *(const f4v*)&P[buf][3][t][l15 * 4] * hv[3];
                float* mp = msg + pos * 64 + l15 * 4;
                if (c == 0) *(f4v*)mp = part;
                else *(f4v*)mp = *(const f4v*)mp + part;
            }
        } else {  // bias chunk: hv == (1,0,0,0)
#pragma unroll
            for (int il = 0; il < MREG; ++il) {
                int i = ib + il;
                if (i < ie) m[il] += *(const f4v*)&P[buf][0][elt[i]][l15 * 4];
            }
            for (int i = CAP + grp; i < cnt_full; i += 16) {
                int pos = e0 + i;
                int t = esrc[ebs[pos]] - n0;
                float* mp = msg + pos * 64 + l15 * 4;
                *(f4v*)mp = *(const f4v*)mp + *(const f4v*)&P[buf][0][t][l15 * 4];
            }
        }
        // stage next h slab (post-barrier, opposite parity vs readers)
        if (hok) *(f4v*)&hC[(c + 1) & 1][tid][0] = hn;
    }

    // flush register messages, coalesced
#pragma unroll
    for (int il = 0; il < MREG; ++il) {
        int i = ib + il;
        if (i < ie) *(f4v*)(msg + (e0 + i) * 64 + l15 * 4) = m[il];
    }
}

// ---------------------- dst-gather mean, massively parallel (1M threads)
// agg[n][o] = mean_{p in dst-CSR(n)} msg[dlist[p]][o]
__global__ __launch_bounds__(256) void k_agg(const float* __restrict__ msg,
                                             const int* __restrict__ dlist,
                                             const int* __restrict__ doff,
                                             float* __restrict__ agg) {
    int idx = blockIdx.x * 256 + threadIdx.x;
    int n = idx >> 6, o = idx & 63;
    int pa = doff[n], pb = doff[n + 1];
    float s = 0.f;
    for (int p = pa; p < pb; ++p) s += msg[(size_t)dlist[p] * 64 + o];
    agg[idx] = s / fmaxf((float)(pb - pa), 1.f);
}

// ------------- NNConv root GEMM + agg + GraphNorm + residual + split
__global__ __launch_bounds__(256) void k_conv_gn(
    const float* __restrict__ agg, const float* __restrict__ rootw,
    const float* __restrict__ convb, const float* __restrict__ gnsc,
    const float* __restrict__ gnw, const float* __restrict__ gnb,
    float* __restrict__ xb, unsigned short* __restrict__ xh,
    unsigned short* __restrict__ xm, unsigned short* __restrict__ xl) {
    __shared__ float xs[128][64];
    __shared__ float Ws[64][64];
    __shared__ float xcs[128][64];
    __shared__ float r1[4][64], r2[4][64], mv[64], rs[64];
    int g = blockIdx.x, tid = threadIdx.x;
    int o = tid & 63, rr = tid >> 6;
    int base = g * 128 * 64;
    for (int i = tid; i < 2048; i += 256) {
        *(f4v*)&xs[0][i * 4] = *(const f4v*)(xb + base + i * 4);
        if (i < 1024) *(f4v*)&Ws[0][i * 4] = *(const f4v*)(rootw + i * 4);
    }
    __syncthreads();
    float cb = convb[o];
    float ls = 0.f, ls2 = 0.f;
    for (int r = rr; r < 128; r += 4) {
        float acc = cb + agg[base + r * 64 + o];
        for (int d = 0; d < 64; ++d) acc += xs[r][d] * Ws[d][o];
        acc = fmaxf(acc, 0.f);
        xcs[r][o] = acc;
        ls += acc;
        ls2 += acc * acc;
    }
    r1[rr][o] = ls;
    r2[rr][o] = ls2;
    __syncthreads();
    if (tid < 64) {
        float sum = r1[0][tid] + r1[1][tid] + r1[2][tid] + r1[3][tid];
        float sum2 = r2[0][tid] + r2[1][tid] + r2[2][tid] + r2[3][tid];
        float m = sum * (1.f / 128.f);
        float ex2 = sum2 * (1.f / 128.f);
        float sc = gnsc[tid];
        float var = ex2 - (2.f * sc - sc * sc) * m * m;
        mv[tid] = m;
        rs[tid] = rsqrtf(var + 1e-5f);
    }
    __syncthreads();
    float sc = gnsc[o], wv = gnw[o], bv = gnb[o], mo = mv[o], rv = rs[o];
    for (int r = rr; r < 128; r += 4) {
        int idx = base + r * 64 + o;
        float xn = wv * (xcs[r][o] - sc * mo) * rv + bv + xs[r][o];
        xb[idx] = xn;
        splitw3(xn, &xh[idx], &xm[idx], &xl[idx]);
    }
}

// ------------------------------------- Set2Set (3 steps) + head, one kernel
__global__ __launch_bounds__(256) void k_s2s(const float* __restrict__ x,
                                             const float* __restrict__ wih,
                                             const float* __restrict__ whh,
                                             const float* __restrict__ bih,
                                             const float* __restrict__ bhh,
                                             const float* __restrict__ hw1,
                                             const float* __restrict__ hb1,
                                             const float* __restrict__ hw2,
                                             const float* __restrict__ hb2,
                                             float* __restrict__ out) {
    int g = blockIdx.x, tid = threadIdx.x;
    __shared__ float xg[128][64];
    __shared__ float qs[128];
    __shared__ float hhS[64], ccS[64];
    __shared__ float gl[256];
    __shared__ float ev[128];
    __shared__ float S[4][64];
    __shared__ float red[2];
    for (int i = tid; i < 8192; i += 256)
        xg[i >> 6][i & 63] = x[(g * 128 + (i >> 6)) * 64 + (i & 63)];
    if (tid < 128) qs[tid] = 0.f;
    if (tid < 64) { hhS[tid] = 0.f; ccS[tid] = 0.f; }
    __syncthreads();

    for (int step = 0; step < 3; ++step) {
        float acc = bih[tid] + bhh[tid];
        const float* wr = wih + tid * 128;
        for (int i = 0; i < 128; ++i) acc += qs[i] * wr[i];
        const float* w2r = whh + tid * 64;
        for (int i = 0; i < 64; ++i) acc += hhS[i] * w2r[i];
        gl[tid] = acc;
        __syncthreads();
        if (tid < 64) {
            float ig = 1.f / (1.f + expf(-gl[tid]));
            float fg = 1.f / (1.f + expf(-gl[64 + tid]));
            float gg = tanhf(gl[128 + tid]);
            float og = 1.f / (1.f + expf(-gl[192 + tid]));
            float cnew = fg * ccS[tid] + ig * gg;
            ccS[tid] = cnew;
            hhS[tid] = og * tanhf(cnew);
        }
        __syncthreads();
        if (tid < 128) {
            float s = 0.f;
            for (int c = 0; c < 64; ++c) s += xg[tid][c] * hhS[c];
            ev[tid] = s;
        }
        __syncthreads();
        if (tid < 64) {
            float mx = fmaxf(ev[tid], ev[tid + 64]);
            for (int off = 32; off > 0; off >>= 1) mx = fmaxf(mx, __shfl_down(mx, off));
            if (tid == 0) red[0] = mx;
        }
        __syncthreads();
        float emax = red[0];
        if (tid < 128) ev[tid] = expf(ev[tid] - emax);
        __syncthreads();
        if (tid < 64) {
            float sm = ev[tid] + ev[tid + 64];
            for (int off = 32; off > 0; off >>= 1) sm += __shfl_down(sm, off);
            if (tid == 0) red[1] = sm;
        }
        __syncthreads();
        float denom = red[1];
        int c = tid & 63, rr = tid >> 6;
        float p = 0.f;
        for (int n = rr; n < 128; n += 4) p += ev[n] * xg[n][c];
        S[rr][c] = p;
        __syncthreads();
        if (tid < 64) {
            float r = (S[0][tid] + S[1][tid] + S[2][tid] + S[3][tid]) / denom;
            qs[tid] = hhS[tid];
            qs[64 + tid] = r;
        }
        __syncthreads();
    }

    if (tid < 64) {
        float acc = hb1[tid];
        for (int i = 0; i < 128; ++i) acc += qs[i] * hw1[i * 64 + tid];
        acc = fmaxf(acc, 0.f);
        float v = acc * hw2[tid];
        for (int off = 32; off > 0; off >>= 1) v += __shfl_down(v, off);
        if (tid == 0) out[g] = v + hb2[0];
    }
}

// -------------------------------------------------------------------- launch
extern "C" void kernel_launch(void* const* d_in, const int* in_sizes, int n_in,
                              void* d_out, int out_size, void* d_ws, size_t ws_size,
                              hipStream_t stream) {
    (void)in_sizes; (void)n_in; (void)out_size; (void)ws_size;
    const float* x_in  = (const float*)d_in[0];
    const int*   eidx  = (const int*)d_in[1];
    const float* eattr = (const float*)d_in[2];
    const float* lin0w = (const float*)d_in[4];
    const float* lin0b = (const float*)d_in[5];
    const float* mw1   = (const float*)d_in[6];
    const float* mb1   = (const float*)d_in[7];
    const float* mw2   = (const float*)d_in[8];
    const float* mb2   = (const float*)d_in[9];
    const float* rootw = (const float*)d_in[10];
    const float* convb = (const float*)d_in[11];
    const float* gnw   = (const float*)d_in[12];
    const float* gnb   = (const float*)d_in[13];
    const float* gnsc  = (const float*)d_in[14];
    const float* wih   = (const float*)d_in[15];
    const float* whh   = (const float*)d_in[16];
    const float* bih   = (const float*)d_in[17];
    const float* bhh   = (const float*)d_in[18];
    const float* hw1   = (const float*)d_in[19];
    const float* hb1   = (const float*)d_in[20];
    const float* hw2   = (const float*)d_in[21];
    const float* hb2   = (const float*)d_in[22];
    float* out = (float*)d_out;

    const int* esrc = eidx;
    const int* edst = eidx + N_EDGES;

    float* xb  = (float*)d_ws;                 // 1,048,576 f
    float* h_s = xb + 1048576;                 // 4,194,304 f
    float* agg = h_s;                          // alias: h_s dead when k_agg runs
    float* msg = h_s + 4194304;                // 4,194,304 f
    unsigned short* xh   = (unsigned short*)(msg + 4194304);  // 1,048,576 us each
    unsigned short* xm   = xh + 1048576;
    unsigned short* xl   = xm + 1048576;
    unsigned short* w2fh = xl + 1048576;       // 3*LFRAG us each
    unsigned short* w2fm = w2fh + 3 * LFRAG;
    unsigned short* w2fl = w2fm + 3 * LFRAG;
    int* deg     = (int*)(w2fl + 3 * LFRAG);
    int* cntd    = deg + N_NODES;
    int* soff    = cntd + N_NODES;
    int* doff    = soff + (N_NODES + 1);
    int* cursor  = doff + (N_NODES + 1);
    int* cursor2 = cursor + N_NODES;
    int* ebs     = cursor2 + N_NODES;
    int* dlist   = ebs + N_EDGES;

    hipMemsetAsync(deg, 0, sizeof(int) * 2 * N_NODES, stream);

    k_w2prep<<<3 * 68, 256, 0, stream>>>(mw2, mb2, w2fh, w2fm, w2fl);
    k_hist<<<N_EDGES / 256, 256, 0, stream>>>(esrc, edst, deg, cntd);
    k_scan2<<<2, 256, 0, stream>>>(deg, cntd, soff, doff, cursor, cursor2);
    k_fill_src<<<N_EDGES / 256, 256, 0, stream>>>(esrc, cursor, ebs);
    k_sortseg<<<N_NODES / 256, 256, 0, stream>>>(soff, ebs);
    k_fill_dl<<<N_EDGES / 256, 256, 0, stream>>>(ebs, edst, cursor2, dlist);
    k_sortseg<<<N_NODES / 256, 256, 0, stream>>>(doff, dlist);

    k_lin0<<<N_NODES / 64, 256, 0, stream>>>(x_in, lin0w, lin0b, xb, xh, xm, xl);

    for (int l = 0; l < 3; ++l) {
        k_hgemm<<<N_EDGES / 64, 256, 0, stream>>>(eattr, mw1 + l * 1024, mb1 + l * 64,
                                                  ebs, h_s);
        k_fused<<<N_NODES / TNF, 256, 0, stream>>>(
            xh, xm, xl,
            w2fh + (size_t)l * LFRAG, w2fm + (size_t)l * LFRAG, w2fl + (size_t)l * LFRAG,
            h_s, soff, ebs, esrc, msg);
        k_agg<<<N_NODES * 64 / 256, 256, 0, stream>>>(msg, dlist, doff, agg);
        k_conv_gn<<<N_GRAPH, 256, 0, stream>>>(agg, rootw + l * 4096,
                                               convb + l * 64, gnsc + l * 64,
                                               gnw + l * 64, gnb + l * 64, xb,
                                               xh, xm, xl);
    }

    k_s2s<<<N_GRAPH, 256, 0, stream>>>(xb, wih, whh, bih, bhh,
                                       hw1, hb1, hw2, hb2, out);
}